// Round 5
// baseline (468.878 us; speedup 1.0000x reference)
//
#include <hip/hip_runtime.h>

#define N_NODES 50000
#define N_EDGES 800000
#define DIM 128
#define NLAYERS 3
#define NGRAPH 512
#define SCAN_NB ((N_NODES + 255) / 256)   // 196

typedef __attribute__((ext_vector_type(8)))  __bf16 bf16x8;
typedef __attribute__((ext_vector_type(16))) float  f32x16;

// ---------------------------------------------------------------- fp32 -> bf16 cast
__global__ __launch_bounds__(256) void k_cast(const float* __restrict__ in,
                                              __bf16* __restrict__ out, int n) {
    int i = blockIdx.x * blockDim.x + threadIdx.x;
    int base = i * 8;
    if (base >= n) return;
    float4 a = *(const float4*)(in + base);
    float4 b = *(const float4*)(in + base + 4);
    bf16x8 o;
    o[0] = (__bf16)a.x; o[1] = (__bf16)a.y; o[2] = (__bf16)a.z; o[3] = (__bf16)a.w;
    o[4] = (__bf16)b.x; o[5] = (__bf16)b.y; o[6] = (__bf16)b.z; o[7] = (__bf16)b.w;
    *(bf16x8*)(out + base) = o;
}

// ---------------------------------------------------------------- degree
__global__ __launch_bounds__(256) void k_degree(const int* __restrict__ dst,
                                                int* __restrict__ cnt) {
    int i = blockIdx.x * blockDim.x + threadIdx.x;
    if (i < N_EDGES) atomicAdd(&cnt[dst[i]], 1);
}

// ---------------------------------------------------------------- hierarchical scan
__global__ __launch_bounds__(256) void k_scan1(const int* __restrict__ cnt,
                                               int* __restrict__ off,
                                               int* __restrict__ bsum) {
    __shared__ int s[256];
    int b = blockIdx.x, t = threadIdx.x;
    int i = b * 256 + t;
    int v = (i < N_NODES) ? cnt[i] : 0;
    s[t] = v; __syncthreads();
#pragma unroll
    for (int d = 1; d < 256; d <<= 1) {
        int nv = (t >= d) ? s[t - d] : 0;
        __syncthreads();
        s[t] += nv;
        __syncthreads();
    }
    if (i < N_NODES) off[i] = s[t] - v;
    if (t == 255) bsum[b] = s[255];
}

__global__ __launch_bounds__(256) void k_scan2(const int* __restrict__ bsum,
                                               int* __restrict__ boff,
                                               int* __restrict__ offN) {
    __shared__ int s[256];
    int t = threadIdx.x;
    int v = (t < SCAN_NB) ? bsum[t] : 0;
    s[t] = v; __syncthreads();
#pragma unroll
    for (int d = 1; d < 256; d <<= 1) {
        int nv = (t >= d) ? s[t - d] : 0;
        __syncthreads();
        s[t] += nv;
        __syncthreads();
    }
    boff[t] = s[t] - v;
    if (t == 255) *offN = s[255];
}

__global__ __launch_bounds__(256) void k_scan3(int* __restrict__ off,
                                               const int* __restrict__ boff) {
    int b = blockIdx.x, t = threadIdx.x;
    int i = b * 256 + t;
    if (i < N_NODES) off[i] += boff[b];
}

// ---------------------------------------------------------------- scatter to CSR (src only)
__global__ __launch_bounds__(256) void k_scatter(const int* __restrict__ src,
                                                 const int* __restrict__ dst,
                                                 const int* __restrict__ off,
                                                 int* __restrict__ cursor,
                                                 int* __restrict__ src_s) {
    int i = blockIdx.x * blockDim.x + threadIdx.x;
    if (i < N_EDGES) {
        int d = dst[i];
        int pos = off[d] + atomicAdd(&cursor[d], 1);
        src_s[pos] = src[i];
    }
}

// ---------------------------------------------------------------- MFMA GEMM: out = X @ W.T + b
__global__ __launch_bounds__(256) void k_gemm_mfma(
    const __bf16* __restrict__ Xb,
    const __bf16* __restrict__ Wq, const __bf16* __restrict__ Wk,
    const __bf16* __restrict__ Wv, const __bf16* __restrict__ Wsk,
    const float* __restrict__ Bq, const float* __restrict__ Bk,
    const float* __restrict__ Bv, const float* __restrict__ Bs,
    __bf16* __restrict__ Oq, __bf16* __restrict__ Okv,
    float* __restrict__ Osk) {
    const int wsel = blockIdx.y;
    const __bf16* W = (wsel == 0) ? Wq : (wsel == 1) ? Wk : (wsel == 2) ? Wv : Wsk;
    const float*  B = (wsel == 0) ? Bq : (wsel == 1) ? Bk : (wsel == 2) ? Bv : Bs;

    int t = threadIdx.x;
    int wave = t >> 6, l = t & 63;
    int lo5 = l & 31, hi = l >> 5;
    int row0 = blockIdx.x * 32;
    int col0 = wave * 32;

    const bf16x8* arow = (const bf16x8*)(Xb + (size_t)(row0 + lo5) * DIM + hi * 8);
    const bf16x8* brow = (const bf16x8*)(W  + (size_t)(col0 + lo5) * DIM + hi * 8);

    f32x16 acc = {};
#pragma unroll
    for (int kt = 0; kt < 8; ++kt)
        acc = __builtin_amdgcn_mfma_f32_32x32x16_bf16(arow[kt * 2], brow[kt * 2], acc, 0, 0, 0);

    float bias = B[col0 + lo5];
    if (wsel == 3) {
#pragma unroll
        for (int r = 0; r < 16; ++r) {
            int row = row0 + (r & 3) + 8 * (r >> 2) + 4 * hi;
            if (row < N_NODES)
                Osk[(size_t)row * DIM + col0 + lo5] = acc[r] + bias;
        }
    } else {
        __bf16* O; size_t stride; int coff;
        if (wsel == 0) { O = Oq;  stride = DIM;     coff = 0; }
        else           { O = Okv; stride = 2 * DIM; coff = (wsel == 2) ? DIM : 0; }
#pragma unroll
        for (int r = 0; r < 16; ++r) {
            int row = row0 + (r & 3) + 8 * (r >> 2) + 4 * hi;
            if (row < N_NODES)
                O[(size_t)row * stride + coff + col0 + lo5] = (__bf16)(acc[r] + bias);
        }
    }
}

// ---------------------------------------------------------------- fused alpha + softmax + aggregate (+skip+relu)
// 1 wave per node, 8x8-lane groups; group g handles edges start+g, start+g+8, ...
// branchless online softmax, 1-deep register prefetch, butterfly merge.
__global__ __launch_bounds__(256) void k_edge_fused(const __bf16* __restrict__ q,
                                                    const __bf16* __restrict__ kv,
                                                    const float* __restrict__ skip,
                                                    const int* __restrict__ src_s,
                                                    const int* __restrict__ off,
                                                    float* __restrict__ xout,
                                                    __bf16* __restrict__ xb) {
    int t = threadIdx.x;
    int w = t >> 6, l = t & 63;
    int n = blockIdx.x * 4 + w;
    if (n >= N_NODES) return;
    int start = off[n], end = off[n + 1];
    int g = l >> 3, gl = l & 7;          // 8 groups of 8 lanes; lane covers dims [gl*16, gl*16+16)

    // q fragment (16 dims) pre-converted to fp32
    float qf[16];
    {
        const bf16x8* qr = (const bf16x8*)(q + (size_t)n * DIM + gl * 16);
        bf16x8 q0 = qr[0], q1 = qr[1];
#pragma unroll
        for (int j = 0; j < 8; ++j) { qf[j] = (float)q0[j]; qf[8 + j] = (float)q1[j]; }
    }

    float m = -INFINITY, denom = 0.f;
    float facc[16] = {};

    int e0 = start + g;
    bf16x8 kA0, kA1, vA0, vA1;
    if (e0 < end) {
        int sA = src_s[e0];
        const bf16x8* r = (const bf16x8*)(kv + (size_t)sA * (2 * DIM) + gl * 16);
        kA0 = r[0]; kA1 = r[1];
        vA0 = r[DIM / 8]; vA1 = r[DIM / 8 + 1];
    }

    for (int e = e0; e < end; e += 8) {
        // prefetch next edge for this group
        bf16x8 kB0, kB1, vB0, vB1;
        int en = e + 8;
        if (en < end) {
            int sB = src_s[en];
            const bf16x8* r = (const bf16x8*)(kv + (size_t)sB * (2 * DIM) + gl * 16);
            kB0 = r[0]; kB1 = r[1];
            vB0 = r[DIM / 8]; vB1 = r[DIM / 8 + 1];
        }
        // dot(q, k) over this lane's 16 dims, then 3-step reduce across the 8-lane group
        float p = 0.f;
#pragma unroll
        for (int j = 0; j < 8; ++j) p += qf[j] * (float)kA0[j];
#pragma unroll
        for (int j = 0; j < 8; ++j) p += qf[8 + j] * (float)kA1[j];
        p += __shfl_xor(p, 4, 64);
        p += __shfl_xor(p, 2, 64);
        p += __shfl_xor(p, 1, 64);
        p *= 0.08838834764831845f;       // 1/sqrt(128)

        // branchless online softmax update
        float newm = fmaxf(m, p);
        float sc  = __expf(m - newm);    // 0 on first edge (m = -inf)
        float wgt = __expf(p - newm);
        denom = denom * sc + wgt;
#pragma unroll
        for (int j = 0; j < 8; ++j) facc[j]     = facc[j]     * sc + wgt * (float)vA0[j];
#pragma unroll
        for (int j = 0; j < 8; ++j) facc[8 + j] = facc[8 + j] * sc + wgt * (float)vA1[j];
        m = newm;

        kA0 = kB0; kA1 = kB1; vA0 = vB0; vA1 = vB1;
    }

    // merge the 8 groups (butterfly over lane bits 3,4,5) with softmax rescale
#pragma unroll
    for (int dlt = 8; dlt <= 32; dlt <<= 1) {
        float m_o = __shfl_xor(m, dlt, 64);
        float d_o = __shfl_xor(denom, dlt, 64);
        float f_o[16];
#pragma unroll
        for (int j = 0; j < 16; ++j) f_o[j] = __shfl_xor(facc[j], dlt, 64);
        float newm = fmaxf(m, m_o);
        float s_s = (m == newm)   ? 1.f : __expf(m - newm);
        float s_o = (m_o == newm) ? 1.f : __expf(m_o - newm);
        denom = denom * s_s + d_o * s_o;
#pragma unroll
        for (int j = 0; j < 16; ++j) facc[j] = facc[j] * s_s + f_o[j] * s_o;
        m = newm;
    }
    float inv = (denom > 0.f) ? 1.f / denom : 0.f;

    if (g < 2) {
        const float* skrow = skip + (size_t)n * DIM + gl * 16;
        float o[16];
#pragma unroll
        for (int j4 = 0; j4 < 4; ++j4) {
            float4 s4 = *(const float4*)(skrow + j4 * 4);
            o[j4 * 4 + 0] = s4.x; o[j4 * 4 + 1] = s4.y;
            o[j4 * 4 + 2] = s4.z; o[j4 * 4 + 3] = s4.w;
        }
#pragma unroll
        for (int j = 0; j < 16; ++j) o[j] = fmaxf(o[j] + facc[j] * inv, 0.f);
        if (g == 0) {
            float* xrow = xout + (size_t)n * DIM + gl * 16;
#pragma unroll
            for (int j4 = 0; j4 < 4; ++j4)
                *(float4*)(xrow + j4 * 4) = make_float4(o[j4 * 4 + 0], o[j4 * 4 + 1],
                                                        o[j4 * 4 + 2], o[j4 * 4 + 3]);
        } else {
            bf16x8 ob0, ob1;
#pragma unroll
            for (int j = 0; j < 8; ++j) { ob0[j] = (__bf16)o[j]; ob1[j] = (__bf16)o[8 + j]; }
            bf16x8* xrow = (bf16x8*)(xb + (size_t)n * DIM + gl * 16);
            xrow[0] = ob0; xrow[1] = ob1;
        }
    }
}

// ---------------------------------------------------------------- mean pool
__global__ __launch_bounds__(256) void k_pool(const float* __restrict__ x,
                                              const int* __restrict__ batch,
                                              float* __restrict__ out) {
    __shared__ float sacc[4][DIM];
    int g = blockIdx.x;
    int t = threadIdx.x;
    int w = t >> 6, l = t & 63;
    int lo = 0, hi = N_NODES;
    while (lo < hi) { int mid = (lo + hi) >> 1; if (batch[mid] < g) lo = mid + 1; else hi = mid; }
    int s0 = lo;
    hi = N_NODES;
    while (lo < hi) { int mid = (lo + hi) >> 1; if (batch[mid] < g + 1) lo = mid + 1; else hi = mid; }
    int s1 = lo;
    float a0 = 0.f, a1 = 0.f;
    for (int n = s0 + w; n < s1; n += 4) {
        float2 xr = *(const float2*)(x + (size_t)n * DIM + l * 2);
        a0 += xr.x; a1 += xr.y;
    }
    sacc[w][l * 2] = a0; sacc[w][l * 2 + 1] = a1;
    __syncthreads();
    if (t < DIM) {
        float s = sacc[0][t] + sacc[1][t] + sacc[2][t] + sacc[3][t];
        int cnt = s1 - s0;
        out[(size_t)g * DIM + t] = s / (float)((cnt > 0) ? cnt : 1);
    }
}

// ----------------------------------------------------------------
extern "C" void kernel_launch(void* const* d_in, const int* in_sizes, int n_in,
                              void* d_out, int out_size, void* d_ws, size_t ws_size,
                              hipStream_t stream) {
    const float* x0   = (const float*)d_in[0];
    const int*  eidx  = (const int*)d_in[1];
    const int*  batch = (const int*)d_in[2];
    const float* Wq = (const float*)d_in[3];
    const float* bq = (const float*)d_in[4];
    const float* Wk = (const float*)d_in[5];
    const float* bk = (const float*)d_in[6];
    const float* Wv = (const float*)d_in[7];
    const float* bv = (const float*)d_in[8];
    const float* Ws = (const float*)d_in[9];
    const float* bs = (const float*)d_in[10];
    float* out = (float*)d_out;

    const int* src = eidx;
    const int* dst = eidx + N_EDGES;

    char* ws = (char*)d_ws;
    size_t p = 0;
    auto alloc = [&](size_t bytes) -> void* {
        void* r = ws + p;
        p = (p + bytes + 255) & ~(size_t)255;
        return r;
    };
    int*    off    = (int*)alloc((N_NODES + 1) * sizeof(int));
    int*    cnt    = (int*)alloc(N_NODES * sizeof(int));
    int*    bsum   = (int*)alloc(256 * sizeof(int));
    int*    boff   = (int*)alloc(256 * sizeof(int));
    int*    src_s  = (int*)alloc(N_EDGES * sizeof(int));
    __bf16* Xb     = (__bf16*)alloc((size_t)N_NODES * DIM * sizeof(__bf16));
    __bf16* qb     = (__bf16*)alloc((size_t)N_NODES * DIM * sizeof(__bf16));
    __bf16* kvb    = (__bf16*)alloc((size_t)N_NODES * 2 * DIM * sizeof(__bf16));
    float*  s1     = (float*)alloc((size_t)N_NODES * DIM * sizeof(float));
    __bf16* Wqb    = (__bf16*)alloc((size_t)NLAYERS * DIM * DIM * sizeof(__bf16));
    __bf16* Wkb    = (__bf16*)alloc((size_t)NLAYERS * DIM * DIM * sizeof(__bf16));
    __bf16* Wvb    = (__bf16*)alloc((size_t)NLAYERS * DIM * DIM * sizeof(__bf16));
    __bf16* Wsb    = (__bf16*)alloc((size_t)NLAYERS * DIM * DIM * sizeof(__bf16));

    // ---- casts
    {
        int nx = N_NODES * DIM;
        k_cast<<<(nx / 8 + 255) / 256, 256, 0, stream>>>(x0, Xb, nx);
        int nw = NLAYERS * DIM * DIM;
        int gw = (nw / 8 + 255) / 256;
        k_cast<<<gw, 256, 0, stream>>>(Wq, Wqb, nw);
        k_cast<<<gw, 256, 0, stream>>>(Wk, Wkb, nw);
        k_cast<<<gw, 256, 0, stream>>>(Wv, Wvb, nw);
        k_cast<<<gw, 256, 0, stream>>>(Ws, Wsb, nw);
    }

    // ---- build CSR
    hipMemsetAsync(cnt, 0, N_NODES * sizeof(int), stream);
    k_degree<<<(N_EDGES + 255) / 256, 256, 0, stream>>>(dst, cnt);
    k_scan1<<<SCAN_NB, 256, 0, stream>>>(cnt, off, bsum);
    k_scan2<<<1, 256, 0, stream>>>(bsum, boff, off + N_NODES);
    k_scan3<<<SCAN_NB, 256, 0, stream>>>(off, boff);
    hipMemsetAsync(cnt, 0, N_NODES * sizeof(int), stream);
    k_scatter<<<(N_EDGES + 255) / 256, 256, 0, stream>>>(src, dst, off, cnt, src_s);

    // ---- layers
    for (int l = 0; l < NLAYERS; ++l) {
        const __bf16* wq = Wqb + (size_t)l * DIM * DIM;
        const __bf16* wk = Wkb + (size_t)l * DIM * DIM;
        const __bf16* wv = Wvb + (size_t)l * DIM * DIM;
        const __bf16* wsk = Wsb + (size_t)l * DIM * DIM;
        const float* biq = bq + (size_t)l * DIM;
        const float* bik = bk + (size_t)l * DIM;
        const float* biv = bv + (size_t)l * DIM;
        const float* bis = bs + (size_t)l * DIM;

        dim3 ggrid((N_NODES + 31) / 32, 4);
        k_gemm_mfma<<<ggrid, 256, 0, stream>>>(Xb, wq, wk, wv, wsk,
                                               biq, bik, biv, bis,
                                               qb, kvb, s1);
        k_edge_fused<<<(N_NODES + 3) / 4, 256, 0, stream>>>(qb, kvb, s1, src_s, off, s1, Xb);
    }

    // ---- mean pool
    k_pool<<<NGRAPH, 256, 0, stream>>>(s1, batch, out);
}